// Round 5
// baseline (112.921 us; speedup 1.0000x reference)
//
#include <hip/hip_runtime.h>
#include <math.h>

#define NPG 128      // nodes per graph
#define HID 64
#define ICH 151
#define EPG 2048     // edges per graph
#define TPB 512      // 8 waves
#define EPT (EPG / TPB)
#define XSS 168      // x LDS row stride, bf16 (336B: 2-way banks, 16B-aligned)
#define BTS 168      // W1^T row stride, bf16
#define HTS 136      // h^T LDS row stride, bf16
#define AS  132      // A row stride, f32 (528B: 2-way banks, 16B-aligned)

typedef __attribute__((ext_vector_type(8))) short  short8;   // bf16x8 frag
typedef __attribute__((ext_vector_type(4))) float  floatx4;  // f32x4 acc

static __device__ __forceinline__ unsigned short f2bf(float v) {
    unsigned u = __builtin_bit_cast(unsigned, v);
    return (unsigned short)((u + 0x7fffu + ((u >> 16) & 1u)) >> 16);
}

// ---------------- Kernel 1: h = bf16(x) @ bf16(W1) -> hg[g][ch][node] ----
__global__ __launch_bounds__(TPB, 4) void gcn_gemm(
    const float* __restrict__ x, const float* __restrict__ W1,
    short* __restrict__ hg)
{
    __shared__ __align__(16) short xs[NPG * XSS];   // 43008 B (ht aliases)
    __shared__ __align__(16) short bt[HID * BTS];   // 21504 B
    short* ht = xs;                                  // [64][HTS] after frag read

    const int t = threadIdx.x, g = blockIdx.x;
    const int lane = t & 63, wv = t >> 6;
    const int c16 = lane & 15, kq = (lane >> 4) * 8;

    // stage W1^T bf16 (k-pad zeroed)
    {
        const int c = t & 63, k0 = (t >> 6) * 2;
        for (int k = k0; k < BTS; k += 16) {
            float w0 = (k     < ICH) ? W1[k * HID + c]       : 0.0f;
            float w1 = (k + 1 < ICH) ? W1[(k + 1) * HID + c] : 0.0f;
            *(unsigned*)&bt[c * BTS + k] =
                (unsigned)f2bf(w0) | ((unsigned)f2bf(w1) << 16);
        }
    }
    // stage x slab: coalesced float4 reads -> bf16 LDS tile
    {
        const float4* xg = (const float4*)(x + (size_t)g * (NPG * ICH));
        for (int p = t; p < NPG * ICH / 4; p += TPB) {
            float4 v = xg[p];
            int e0 = p * 4;
            #pragma unroll
            for (int j = 0; j < 4; ++j) {
                unsigned e = (unsigned)(e0 + j);
                unsigned r = e / 151u, c = e - r * 151u;
                xs[r * XSS + c] = (short)f2bf(((const float*)&v)[j]);
            }
        }
        for (int idx = t; idx < NPG * 9; idx += TPB) {   // zero k 151..159
            int r = idx / 9, c = 151 + (idx - r * 9);
            xs[r * XSS + c] = 0;
        }
    }
    __syncthreads();                          // xs, bt ready

    short8 af[5];
    #pragma unroll
    for (int s = 0; s < 5; ++s)
        af[s] = *(const short8*)&xs[(wv * 16 + c16) * XSS + s * 32 + kq];
    __syncthreads();                          // xs dead -> ht alias safe

    #pragma unroll
    for (int n = 0; n < 4; ++n) {
        floatx4 acc = {0.0f, 0.0f, 0.0f, 0.0f};
        #pragma unroll
        for (int s = 0; s < 5; ++s) {
            short8 b = *(const short8*)&bt[(n * 16 + c16) * BTS + s * 32 + kq];
            acc = __builtin_amdgcn_mfma_f32_16x16x32_bf16(af[s], b, acc, 0, 0, 0);
        }
        // D: row = (lane>>4)*4 + r, col = n*16 + c16  -> ht[col][row]
        unsigned lo = (unsigned)f2bf(acc[0]) | ((unsigned)f2bf(acc[1]) << 16);
        unsigned hi = (unsigned)f2bf(acc[2]) | ((unsigned)f2bf(acc[3]) << 16);
        int col = n * 16 + c16;
        int row = wv * 16 + (lane >> 4) * 4;
        *(int2*)&ht[col * HTS + row] = make_int2((int)lo, (int)hi);
    }
    __syncthreads();

    // dump ht -> hg[g][ch][node], fully coalesced dword stores
    {
        unsigned* dst = (unsigned*)(hg + (size_t)g * (HID * NPG));
        #pragma unroll
        for (int j = 0; j < 8; ++j) {
            int p = t + j * TPB;              // dword index 0..4095
            int ch = p >> 6, np = p & 63;     // np = node pair
            dst[ch * 64 + np] = *(const unsigned*)&ht[ch * HTS + 2 * np];
        }
    }
}

// ---------------- Kernel 2: aggregation + readout ------------------------
__global__ __launch_bounds__(TPB, 6) void gcn_agg(
    const int*   __restrict__ erow,    // [E]
    const int*   __restrict__ ecol,    // [E]
    const float* __restrict__ ew,      // [E]
    const short* __restrict__ hg,      // [B][64][128] bf16
    const float* __restrict__ b1,      // [64]
    const float* __restrict__ Wlin,    // [8192]
    const float* __restrict__ blin,    // [1]
    float* __restrict__ out)           // [B]
{
    __shared__ __align__(16) float As[64 * AS];      // 33792 B
    __shared__ float deg[NPG];
    __shared__ float dinv[NPG];
    __shared__ float red[TPB / 64];

    const int t = threadIdx.x, g = blockIdx.x;
    const int lane = t & 63, wv = t >> 6;
    const int c16 = lane & 15, kq = (lane >> 4) * 8;

    if (t < NPG) deg[t] = 1.0f;                      // self-loop weight
    __syncthreads();

    // one edge pass: keep in regs, accumulate degree
    int   er_[EPT];
    int   ec_[EPT];
    float ew_[EPT];
    const int ebase = g * EPG;
    #pragma unroll
    for (int it = 0; it < EPT; ++it) {
        int e = ebase + t + it * TPB;
        er_[it] = erow[e] & (NPG - 1);
        ec_[it] = ecol[e] & (NPG - 1);
        ew_[it] = ew[e];
        atomicAdd(&deg[ec_[it]], ew_[it]);
    }
    __syncthreads();
    if (t < NPG) dinv[t] = rsqrtf(deg[t]);           // deg >= 1 always
    __syncthreads();

    float partial = 0.0f;
    const int mrow = (wv >> 1) * 16 + c16;           // dst row within half
    const short* hgg = hg + (size_t)g * (HID * NPG);

    for (int half = 0; half < 2; ++half) {
        for (int z = t; z < 64 * AS / 4; z += TPB)   // zero A
            ((floatx4*)As)[z] = (floatx4){0.0f, 0.0f, 0.0f, 0.0f};
        __syncthreads();

        #pragma unroll
        for (int it = 0; it < EPT; ++it) {
            int cl = ec_[it];
            if ((cl >> 6) == half) {
                int rl = er_[it];
                atomicAdd(&As[(cl & 63) * AS + rl], dinv[rl] * ew_[it] * dinv[cl]);
            }
        }
        if (t < 64) {                                // diagonal self-loop
            int i = half * 64 + t;
            atomicAdd(&As[t * AS + i], dinv[i] * dinv[i]);
        }
        __syncthreads();

        // A fragments (convert to bf16)
        short8 afr[4];
        #pragma unroll
        for (int ks = 0; ks < 4; ++ks) {
            const float* ap = &As[mrow * AS + ks * 32 + kq];
            floatx4 a0 = *(const floatx4*)ap;
            floatx4 a1 = *(const floatx4*)(ap + 4);
            short8 v;
            v[0] = (short)f2bf(a0[0]); v[1] = (short)f2bf(a0[1]);
            v[2] = (short)f2bf(a0[2]); v[3] = (short)f2bf(a0[3]);
            v[4] = (short)f2bf(a1[0]); v[5] = (short)f2bf(a1[1]);
            v[6] = (short)f2bf(a1[2]); v[7] = (short)f2bf(a1[3]);
            afr[ks] = v;
        }
        #pragma unroll
        for (int nn = 0; nn < 2; ++nn) {
            int nt = (wv & 1) * 2 + nn;
            floatx4 acc = {0.0f, 0.0f, 0.0f, 0.0f};
            #pragma unroll
            for (int ks = 0; ks < 4; ++ks) {
                // B-frag: 8 consecutive src nodes of one channel, contiguous 16B
                short8 b = *(const short8*)&hgg[(nt * 16 + c16) * NPG + ks * 32 + kq];
                acc = __builtin_amdgcn_mfma_f32_16x16x32_bf16(afr[ks], b, acc, 0, 0, 0);
            }
            int col = nt * 16 + c16;
            float b1v = b1[col];
            int row0 = half * 64 + (wv >> 1) * 16 + (lane >> 4) * 4;
            #pragma unroll
            for (int r = 0; r < 4; ++r) {
                float v = fmaxf(acc[r] + b1v, 0.0f);
                partial += v * Wlin[(row0 + r) * HID + col];
            }
        }
        __syncthreads();                             // A reads done before re-zero
    }

    #pragma unroll
    for (int o = 32; o > 0; o >>= 1)
        partial += __shfl_down(partial, o, 64);
    if (lane == 0) red[wv] = partial;
    __syncthreads();
    if (t == 0) {
        float tot = blin[0];
        #pragma unroll
        for (int i = 0; i < TPB / 64; ++i) tot += red[i];
        out[g] = 1.0f / (1.0f + expf(-tot));
    }
}

extern "C" void kernel_launch(void* const* d_in, const int* in_sizes, int n_in,
                              void* d_out, int out_size, void* d_ws, size_t ws_size,
                              hipStream_t stream) {
    const float* x    = (const float*)d_in[0];
    const int*   ei   = (const int*)d_in[1];
    const float* ew   = (const float*)d_in[2];
    const float* W1   = (const float*)d_in[4];
    const float* b1   = (const float*)d_in[5];
    const float* Wlin = (const float*)d_in[6];
    const float* blin = (const float*)d_in[7];
    float* out = (float*)d_out;

    const int E = in_sizes[1] / 2;     // edge_index is [2, E]
    const int B = out_size;            // 2048 graphs

    short* hg = (short*)d_ws;          // [B][64][128] bf16 = 33.6 MB

    gcn_gemm<<<B, TPB, 0, stream>>>(x, W1, hg);
    gcn_agg<<<B, TPB, 0, stream>>>(ei, ei + E, ew, hg, b1, Wlin, blin, out);
}

// Round 6
// 94.705 us; speedup vs baseline: 1.1923x; 1.1923x over previous
//
#include <hip/hip_runtime.h>
#include <math.h>

#define NPG 128      // nodes per graph
#define HID 64
#define ICH 151
#define EPG 2048     // edges per graph
#define TPB 512      // 8 waves
#define EPT (EPG / TPB)
#define XSS 168      // xs row stride, bf16 (336B: 16B-aligned, 2-way banks)
#define BTS 168      // W1^T row stride, bf16
#define HTS 136      // h^T row stride, bf16 (272B: 16B-aligned, 2-way banks)
#define ASS 132      // As row stride, f32 (528B: 16B-aligned, 2-way banks)
#define BT_OFF 21504 // byte offset of bt / As region inside smem

typedef __attribute__((ext_vector_type(8))) short  short8;   // bf16x8 frag
typedef __attribute__((ext_vector_type(4))) float  floatx4;  // f32x4 acc

static __device__ __forceinline__ unsigned short f2bf(float v) {
    unsigned u = __builtin_bit_cast(unsigned, v);
    return (unsigned short)((u + 0x7fffu + ((u >> 16) & 1u)) >> 16);
}

__global__ __launch_bounds__(TPB, 6) void gcn_fused(
    const float* __restrict__ x,       // [N,151]
    const int*   __restrict__ erow,    // [E]
    const int*   __restrict__ ecol,    // [E]
    const float* __restrict__ ew,      // [E]
    const float* __restrict__ W1,      // [151,64] row-major
    const float* __restrict__ b1,      // [64]
    const float* __restrict__ Wlin,    // [8192]
    const float* __restrict__ blin,    // [1]
    float* __restrict__ out)           // [B]
{
    // Phase-aliased LDS:
    //   phase 1: xs  = smem[0 .. 43008)           128x168 bf16 x tile
    //   phase 2: ht  = smem[0 .. 17408)           64x136 bf16 h^T
    //            bt  = smem[21504 .. 43008)       64x168 bf16 W1^T
    //   phase 3: As  = smem[21504 .. 38400)       32x132 f32 quarter-adjacency
    __shared__ __align__(16) char smem[43008];
    __shared__ float deg[NPG];
    __shared__ float dinv[NPG];
    __shared__ float red[TPB / 64];

    short* xs = (short*)smem;
    short* ht = (short*)smem;
    short* bt = (short*)(smem + BT_OFF);
    float* As = (float*)(smem + BT_OFF);

    const int t    = threadIdx.x;
    const int g    = blockIdx.x;
    const int lane = t & 63;
    const int wv   = t >> 6;
    const int c16  = lane & 15;
    const int kq   = (lane >> 4) * 8;

    // ---- early edge loads (coalesced, once) ----
    int   er_[EPT];
    int   ec_[EPT];
    float nw_[EPT];
    const int ebase = g * EPG;
    #pragma unroll
    for (int it = 0; it < EPT; ++it) {
        int e = ebase + t + it * TPB;
        er_[it] = erow[e] & (NPG - 1);
        ec_[it] = ecol[e] & (NPG - 1);
        nw_[it] = ew[e];
    }
    if (t < NPG) deg[t] = 1.0f;                       // self-loop weight

    // ---- coalesced x staging: float4 global reads -> bf16 LDS tile ----
    {
        const float4* xg = (const float4*)(x + (size_t)g * (NPG * ICH));
        for (int p = t; p < NPG * ICH / 4; p += TPB) {
            float4 v = xg[p];
            int e0 = 4 * p;
            #pragma unroll
            for (int j = 0; j < 4; ++j) {
                unsigned e = (unsigned)(e0 + j);
                unsigned r = e / 151u, c = e - 151u * r;
                xs[r * XSS + c] = (short)f2bf(((const float*)&v)[j]);
            }
        }
        for (int idx = t; idx < NPG * 9; idx += TPB) {   // zero k = 151..159
            int r = idx / 9, c = ICH + (idx - 9 * r);
            xs[r * XSS + c] = 0;
        }
    }
    __syncthreads();                                   // sync1: xs + deg-init ready

    // ---- degree atomics (edges already in regs) ----
    #pragma unroll
    for (int it = 0; it < EPT; ++it)
        atomicAdd(&deg[ec_[it]], nw_[it]);

    // ---- A-fragments from LDS (b128, 2-way banks) ----
    short8 af[5];
    #pragma unroll
    for (int s = 0; s < 5; ++s)
        af[s] = *(const short8*)&xs[(wv * 16 + c16) * XSS + s * 32 + kq];
    __syncthreads();                                   // sync2: xs dead, deg done

    // ---- stage W1^T bf16 into bt; dinv ----
    {
        const int c = t & 63, k0 = (t >> 6) * 2;
        for (int k = k0; k < BTS; k += 16) {
            float w0 = (k     < ICH) ? W1[k * HID + c]       : 0.0f;
            float w1 = (k + 1 < ICH) ? W1[(k + 1) * HID + c] : 0.0f;
            *(unsigned*)&bt[c * BTS + k] =
                (unsigned)f2bf(w0) | ((unsigned)f2bf(w1) << 16);
        }
    }
    if (t < NPG) dinv[t] = rsqrtf(deg[t]);             // deg >= 1 always
    __syncthreads();                                   // sync3: bt + dinv ready

    // ---- precompute edge norms (once) ----
    #pragma unroll
    for (int it = 0; it < EPT; ++it)
        nw_[it] = dinv[er_[it]] * nw_[it] * dinv[ec_[it]];

    // ---- GEMM h = x @ W1 -> ht (bf16, [col][row]) ----
    #pragma unroll
    for (int n = 0; n < 4; ++n) {
        floatx4 acc = {0.0f, 0.0f, 0.0f, 0.0f};
        #pragma unroll
        for (int s = 0; s < 5; ++s) {
            short8 b = *(const short8*)&bt[(n * 16 + c16) * BTS + s * 32 + kq];
            acc = __builtin_amdgcn_mfma_f32_16x16x32_bf16(af[s], b, acc, 0, 0, 0);
        }
        // D: row = (lane>>4)*4 + r, col = n*16 + c16  -> ht[col][row]
        unsigned lo = (unsigned)f2bf(acc[0]) | ((unsigned)f2bf(acc[1]) << 16);
        unsigned hi = (unsigned)f2bf(acc[2]) | ((unsigned)f2bf(acc[3]) << 16);
        int col = n * 16 + c16;
        int row = wv * 16 + (lane >> 4) * 4;
        *(int2*)&ht[col * HTS + row] = make_int2((int)lo, (int)hi);
    }
    __syncthreads();                                   // sync4: ht ready, bt dead

    // ---- aggregation in 4 dst-quarters: build As (32x128) then MFMA ----
    float partial = 0.0f;
    const int mt  = wv >> 2;                           // 0..1: m-tile within quarter
    const int nt  = wv & 3;                            // 0..3: n-tile (channels)
    const int col = nt * 16 + c16;
    const float b1v = b1[col];

    for (int q = 0; q < 4; ++q) {
        for (int p = t; p < 32 * ASS / 4; p += TPB)    // zero quarter-A
            ((floatx4*)As)[p] = (floatx4){0.0f, 0.0f, 0.0f, 0.0f};
        __syncthreads();

        #pragma unroll
        for (int it = 0; it < EPT; ++it) {
            int cl = ec_[it];
            if ((cl >> 5) == q)
                atomicAdd(&As[(cl & 31) * ASS + er_[it]], nw_[it]);
        }
        if (t < 32) {                                  // diagonal self-loop
            int i = q * 32 + t;
            atomicAdd(&As[t * ASS + i], dinv[i] * dinv[i]);
        }
        __syncthreads();

        floatx4 acc = {0.0f, 0.0f, 0.0f, 0.0f};
        #pragma unroll
        for (int ks = 0; ks < 4; ++ks) {
            const float* ap = &As[(mt * 16 + c16) * ASS + ks * 32 + kq];
            floatx4 a0 = *(const floatx4*)ap;
            floatx4 a1 = *(const floatx4*)(ap + 4);
            short8 av;
            av[0] = (short)f2bf(a0[0]); av[1] = (short)f2bf(a0[1]);
            av[2] = (short)f2bf(a0[2]); av[3] = (short)f2bf(a0[3]);
            av[4] = (short)f2bf(a1[0]); av[5] = (short)f2bf(a1[1]);
            av[6] = (short)f2bf(a1[2]); av[7] = (short)f2bf(a1[3]);
            short8 b = *(const short8*)&ht[col * HTS + ks * 32 + kq];
            acc = __builtin_amdgcn_mfma_f32_16x16x32_bf16(av, b, acc, 0, 0, 0);
        }
        int node0 = q * 32 + mt * 16 + (lane >> 4) * 4;
        #pragma unroll
        for (int r = 0; r < 4; ++r) {
            float v = fmaxf(acc[r] + b1v, 0.0f);
            partial += v * Wlin[(node0 + r) * HID + col];
        }
        __syncthreads();                               // As reads done before re-zero
    }

    // ---- block reduction + sigmoid ----
    #pragma unroll
    for (int o = 32; o > 0; o >>= 1)
        partial += __shfl_down(partial, o, 64);
    if (lane == 0) red[wv] = partial;
    __syncthreads();
    if (t == 0) {
        float tot = blin[0];
        #pragma unroll
        for (int i = 0; i < TPB / 64; ++i) tot += red[i];
        out[g] = 1.0f / (1.0f + expf(-tot));
    }
}

extern "C" void kernel_launch(void* const* d_in, const int* in_sizes, int n_in,
                              void* d_out, int out_size, void* d_ws, size_t ws_size,
                              hipStream_t stream) {
    const float* x    = (const float*)d_in[0];
    const int*   ei   = (const int*)d_in[1];
    const float* ew   = (const float*)d_in[2];
    const float* W1   = (const float*)d_in[4];
    const float* b1   = (const float*)d_in[5];
    const float* Wlin = (const float*)d_in[6];
    const float* blin = (const float*)d_in[7];
    float* out = (float*)d_out;

    const int E = in_sizes[1] / 2;     // edge_index is [2, E]
    const int B = out_size;            // 2048 graphs

    gcn_fused<<<B, TPB, 0, stream>>>(x, ei, ei + E, ew, W1, b1, Wlin, blin, out);
}